// Round 7
// baseline (244.887 us; speedup 1.0000x reference)
//
#include <hip/hip_runtime.h>

#define B_  4
#define N_  4096   // H*W
#define C_  256
#define D_  32

typedef __attribute__((ext_vector_type(8))) short bf8;   // 8 bf16 (4 VGPRs)
typedef __attribute__((ext_vector_type(4))) float f4;    // MFMA C/D frag

__device__ __forceinline__ unsigned short bft(float f) {
    unsigned u = __builtin_bit_cast(unsigned, f);
    return (unsigned short)((u + 0x8000u) >> 16);
}
// pack two floats to bf16x2 (a->low, b->high)
__device__ __forceinline__ unsigned pk2(float a, float b) {
    unsigned ua = __builtin_bit_cast(unsigned, a) + 0x8000u;
    unsigned ub = __builtin_bit_cast(unsigned, b) + 0x8000u;
    return __builtin_amdgcn_perm(ub, ua, 0x07060302u);
}

// ---------------------------------------------------------------------------
// prep: weights -> bf16. Wqkb[64][256] = Wq rows 0-31, Wk rows 32-63.
// ---------------------------------------------------------------------------
__global__ __launch_bounds__(256) void prep(
    const float* __restrict__ Wq, const float* __restrict__ Wk,
    const float* __restrict__ Wv,
    unsigned short* __restrict__ Wqkb, unsigned short* __restrict__ Wvb)
{
    int i = blockIdx.x * 256 + threadIdx.x;
    if (i < 8192)       Wqkb[i] = bft(Wq[i]);
    else if (i < 16384) Wqkb[i] = bft(Wk[i - 8192]);
    Wvb[i] = bft(Wv[i]);
}

// ---------------------------------------------------------------------------
// qkv: n-tile 64 per block, 512 thr, 8 waves. q pre-scaled by log2(e).
// ---------------------------------------------------------------------------
__global__ __launch_bounds__(512) void qkv(
    const float* __restrict__ x,
    const unsigned short* __restrict__ Wqkb, const unsigned short* __restrict__ Wvb,
    const float* __restrict__ bq, const float* __restrict__ bk,
    const float* __restrict__ bv,
    unsigned short* __restrict__ qb, unsigned short* __restrict__ kb,
    unsigned short* __restrict__ vb)
{
    const int b = blockIdx.y, n0 = blockIdx.x * 64;
    const int t = threadIdx.x;
    const int lane = t & 63, w = t >> 6, c15 = lane & 15, g = lane >> 4;
    const int vr = w & 3, nh = w >> 2;

    __shared__ __align__(16) unsigned short xs[64][264];

    #pragma unroll
    for (int it = 0; it < 8; ++it) {
        int idx = t + 512 * it;
        int c = idx >> 4, q = idx & 15;
        float4 v = *(const float4*)(x + ((size_t)(b * C_ + c)) * N_ + n0 + q * 4);
        xs[q * 4 + 0][c] = bft(v.x);
        xs[q * 4 + 1][c] = bft(v.y);
        xs[q * 4 + 2][c] = bft(v.z);
        xs[q * 4 + 3][c] = bft(v.w);
    }
    __syncthreads();

    f4 qkacc[2]; f4 vacc[2][4];
    const f4 fz = {0.f, 0.f, 0.f, 0.f};
    qkacc[0] = fz; qkacc[1] = fz;
    #pragma unroll
    for (int nt = 0; nt < 2; ++nt)
        #pragma unroll
        for (int ct = 0; ct < 4; ++ct) vacc[nt][ct] = fz;

    const unsigned short* wqk = Wqkb + (vr * 16 + c15) * C_ + g * 8;
    const unsigned short* wv0 = Wvb + (vr * 64 + c15) * C_ + g * 8;
    const unsigned short* xsp = &xs[nh * 32 + c15][g * 8];

    #pragma unroll
    for (int ks = 0; ks < 8; ++ks) {
        bf8 xf0 = *(const bf8*)(xsp + ks * 32);
        bf8 xf1 = *(const bf8*)(xsp + 16 * 264 + ks * 32);
        bf8 af  = *(const bf8*)(wqk + ks * 32);
        qkacc[0] = __builtin_amdgcn_mfma_f32_16x16x32_bf16(af, xf0, qkacc[0], 0, 0, 0);
        qkacc[1] = __builtin_amdgcn_mfma_f32_16x16x32_bf16(af, xf1, qkacc[1], 0, 0, 0);
        #pragma unroll
        for (int ct = 0; ct < 4; ++ct) {
            bf8 bfv = *(const bf8*)(wv0 + ct * 16 * C_ + ks * 32);
            vacc[0][ct] = __builtin_amdgcn_mfma_f32_16x16x32_bf16(xf0, bfv, vacc[0][ct], 0, 0, 0);
            vacc[1][ct] = __builtin_amdgcn_mfma_f32_16x16x32_bf16(xf1, bfv, vacc[1][ct], 0, 0, 0);
        }
    }

    {
        float4 bias = (vr < 2) ? *(const float4*)(bq + (vr & 1) * 16 + 4 * g)
                               : *(const float4*)(bk + (vr & 1) * 16 + 4 * g);
        float sc = (vr < 2) ? 1.44269504f : 1.0f;
        unsigned short* base = (vr < 2) ? qb : kb;
        int d0 = (vr & 1) * 16 + 4 * g;
        #pragma unroll
        for (int nt = 0; nt < 2; ++nt) {
            int n = n0 + (nh * 2 + nt) * 16 + c15;
            f4 a = qkacc[nt];
            uint2 pk;
            pk.x = pk2((a.x + bias.x) * sc, (a.y + bias.y) * sc);
            pk.y = pk2((a.z + bias.z) * sc, (a.w + bias.w) * sc);
            *(uint2*)(base + ((size_t)(b * N_ + n)) * D_ + d0) = pk;
        }
    }
    #pragma unroll
    for (int ct = 0; ct < 4; ++ct) {
        int cout = vr * 64 + ct * 16 + c15;
        float bvv = bv[cout];
        #pragma unroll
        for (int nt = 0; nt < 2; ++nt) {
            f4 a = vacc[nt][ct];
            uint2 pk;
            pk.x = pk2(a.x + bvv, a.y + bvv);
            pk.y = pk2(a.z + bvv, a.w + bvv);
            *(uint2*)(vb + ((size_t)(b * C_ + cout)) * (size_t)N_
                      + n0 + (nh * 2 + nt) * 16 + 4 * g) = pk;
        }
    }
}

// ---------------------------------------------------------------------------
// attn v4: M=64, c-half 128, KT=128, 512 thr = 8 waves, grid 512 = 2 blk/CU.
// launch_bounds(512,2): empirically allows <=128 VGPR (R4: 96) — keeps the
// K/V register pipeline intact ((512,4) capped at 64 and de-pipelined, R5/R6).
// V is double-buffered ONE FULL ITERATION ahead (vfA/vfB, 2x-unrolled loop)
// so V L2 latency is covered by a whole iteration body, not ~150 cyc.
// ---------------------------------------------------------------------------
__global__ __launch_bounds__(512, 2) void attn(
    const unsigned short* __restrict__ qb, const unsigned short* __restrict__ kb,
    const unsigned short* __restrict__ vb, const float* __restrict__ x,
    const float* __restrict__ gamma, float* __restrict__ out)
{
    const int b = blockIdx.z, c0 = blockIdx.y * 128, m0 = blockIdx.x * 64;
    const int t = threadIdx.x;
    const int lane = t & 63, w = t >> 6, c15 = lane & 15, g = lane >> 4;
    const int pm = w & 3, pnh = w >> 2;   // produce role
    const int mh = w & 1, cq = w >> 1;    // consume role

    __shared__ __align__(16) unsigned short Ps[2][64][136];  // 272-B rows
    __shared__ float l_s[2][64];

    const f4 fz = {0.f, 0.f, 0.f, 0.f};

    bf8 qf = *(const bf8*)(qb + ((size_t)(b * N_ + m0 + pm * 16 + c15)) * D_ + g * 8);

    const unsigned short* kptr = kb + ((size_t)(b * N_ + pnh * 64 + c15)) * D_ + g * 8;
    bf8 kf[4];
    #pragma unroll
    for (int ff = 0; ff < 4; ++ff)
        kf[ff] = *(const bf8*)(kptr + (size_t)ff * 16 * D_);
    kptr += (size_t)128 * D_;

    f4 acc[2][2];
    #pragma unroll
    for (int mi = 0; mi < 2; ++mi)
        #pragma unroll
        for (int ct = 0; ct < 2; ++ct) acc[mi][ct] = fz;
    float lrun = 0.f;

    const unsigned short* vptr = vb + ((size_t)(b * C_ + c0 + cq * 32)) * (size_t)N_ + g * 8;

    // preload V for iter 0
    bf8 vfA[4][2], vfB[4][2];
    #pragma unroll
    for (int ki = 0; ki < 4; ++ki)
        #pragma unroll
        for (int ct = 0; ct < 2; ++ct)
            vfA[ki][ct] = *(const bf8*)(vptr + (size_t)(ct * 16 + c15) * N_ + ki * 32);
    vptr += 128;

    auto body = [&](int buf, bf8 (&vcur)[4][2], bf8 (&vnext)[4][2]) {
        // prefetch NEXT iter's V (full-iteration in-flight distance).
        // Last trip reads ~4K elems past vb end — lands in the weight region
        // of d_ws (in-bounds), values unused.
        #pragma unroll
        for (int ki = 0; ki < 4; ++ki)
            #pragma unroll
            for (int ct = 0; ct < 2; ++ct)
                vnext[ki][ct] = *(const bf8*)(vptr + (size_t)(ct * 16 + c15) * N_ + ki * 32);
        vptr += 128;
        // produce S^T = K·Q^T
        f4 s[4];
        #pragma unroll
        for (int ff = 0; ff < 4; ++ff)
            s[ff] = __builtin_amdgcn_mfma_f32_16x16x32_bf16(kf[ff], qf, fz, 0, 0, 0);
        // K prefetch for next iter (last trip lands past kb in vb — safe)
        #pragma unroll
        for (int ff = 0; ff < 4; ++ff)
            kf[ff] = *(const bf8*)(kptr + (size_t)ff * 16 * D_);
        kptr += (size_t)128 * D_;
        // exp2 (q pre-scaled by log2e), pack, write P
        #pragma unroll
        for (int ff = 0; ff < 4; ++ff) {
            float p0 = __builtin_amdgcn_exp2f(s[ff].x);
            float p1 = __builtin_amdgcn_exp2f(s[ff].y);
            float p2 = __builtin_amdgcn_exp2f(s[ff].z);
            float p3 = __builtin_amdgcn_exp2f(s[ff].w);
            lrun += (p0 + p1) + (p2 + p3);
            uint2 pk; pk.x = pk2(p0, p1); pk.y = pk2(p2, p3);
            *(uint2*)&Ps[buf][pm * 16 + c15][(pnh * 4 + ff) * 16 + 4 * g] = pk;
        }
        // light barrier: drain LDS only; global loads stay in flight
        asm volatile("s_waitcnt lgkmcnt(0)\n\ts_barrier" ::: "memory");
        // consume: O += P·V^T (32m x 32c tile, all 128 keys) with vcur
        #pragma unroll
        for (int ki = 0; ki < 4; ++ki) {
            const int kcol = ki * 32 + g * 8;
            bf8 pf0 = *(const bf8*)&Ps[buf][(2 * mh + 0) * 16 + c15][kcol];
            bf8 pf1 = *(const bf8*)&Ps[buf][(2 * mh + 1) * 16 + c15][kcol];
            #pragma unroll
            for (int ct = 0; ct < 2; ++ct) {
                acc[0][ct] = __builtin_amdgcn_mfma_f32_16x16x32_bf16(pf0, vcur[ki][ct], acc[0][ct], 0, 0, 0);
                acc[1][ct] = __builtin_amdgcn_mfma_f32_16x16x32_bf16(pf1, vcur[ki][ct], acc[1][ct], 0, 0, 0);
            }
        }
    };

    for (int it = 0; it < 32; it += 2) {
        body(0, vfA, vfB);
        body(1, vfB, vfA);
    }

    // l: finish per-m sums (reduce over g), publish per n-half
    lrun += __shfl_xor(lrun, 16);
    lrun += __shfl_xor(lrun, 32);
    if (lane < 16) l_s[pnh][pm * 16 + lane] = lrun;
    __syncthreads();

    const float g0 = gamma[0];
    #pragma unroll
    for (int mi = 0; mi < 2; ++mi) {
        const int mrow = (2 * mh + mi) * 16;
        float4 la = *(const float4*)&l_s[0][mrow + 4 * g];
        float4 lb = *(const float4*)&l_s[1][mrow + 4 * g];
        float i0 = 1.f / (la.x + lb.x), i1 = 1.f / (la.y + lb.y);
        float i2 = 1.f / (la.z + lb.z), i3 = 1.f / (la.w + lb.w);
        #pragma unroll
        for (int ct = 0; ct < 2; ++ct) {
            f4 a = acc[mi][ct];
            int c = c0 + (cq * 2 + ct) * 16 + c15;
            size_t base = ((size_t)(b * C_ + c)) * (size_t)N_ + m0 + mrow + 4 * g;
            float4 xv = *(const float4*)(x + base);
            float4 r;
            r.x = g0 * (a.x * i0) + xv.x;
            r.y = g0 * (a.y * i1) + xv.y;
            r.z = g0 * (a.z * i2) + xv.z;
            r.w = g0 * (a.w * i3) + xv.w;
            *(float4*)(out + base) = r;
        }
    }
}

extern "C" void kernel_launch(void* const* d_in, const int* in_sizes, int n_in,
                              void* d_out, int out_size, void* d_ws, size_t ws_size,
                              hipStream_t stream) {
    const float* x     = (const float*)d_in[0];
    const float* Wq    = (const float*)d_in[1];
    const float* bq    = (const float*)d_in[2];
    const float* Wk    = (const float*)d_in[3];
    const float* bk    = (const float*)d_in[4];
    const float* Wv    = (const float*)d_in[5];
    const float* bv    = (const float*)d_in[6];
    const float* gamma = (const float*)d_in[7];
    float* out = (float*)d_out;

    unsigned short* qb   = (unsigned short*)d_ws;
    unsigned short* kb   = qb + (size_t)B_ * N_ * D_;
    unsigned short* vb   = kb + (size_t)B_ * N_ * D_;
    unsigned short* Wqkb = vb + (size_t)B_ * C_ * N_;
    unsigned short* Wvb  = Wqkb + 64 * C_;

    prep<<<256, 256, 0, stream>>>(Wq, Wk, Wv, Wqkb, Wvb);
    qkv<<<dim3(64, 4), 512, 0, stream>>>(x, Wqkb, Wvb, bq, bk, bv, qb, kb, vb);
    attn<<<dim3(64, 2, 4), 512, 0, stream>>>(qb, kb, vb, x, gamma, out);
}

// Round 8
// 187.662 us; speedup vs baseline: 1.3049x; 1.3049x over previous
//
#include <hip/hip_runtime.h>

#define B_  4
#define N_  4096   // H*W
#define C_  256
#define D_  32

typedef __attribute__((ext_vector_type(8))) short bf8;   // 8 bf16 (4 VGPRs)
typedef __attribute__((ext_vector_type(4))) float f4;    // MFMA C/D frag

__device__ __forceinline__ unsigned short bft(float f) {
    unsigned u = __builtin_bit_cast(unsigned, f);
    return (unsigned short)((u + 0x8000u) >> 16);
}
// pack two floats to bf16x2 (a->low, b->high)
__device__ __forceinline__ unsigned pk2(float a, float b) {
    unsigned ua = __builtin_bit_cast(unsigned, a) + 0x8000u;
    unsigned ub = __builtin_bit_cast(unsigned, b) + 0x8000u;
    return __builtin_amdgcn_perm(ub, ua, 0x07060302u);
}

// ---------------------------------------------------------------------------
// prep: weights -> bf16. Wqkb[64][256] = Wq rows 0-31, Wk rows 32-63.
// ---------------------------------------------------------------------------
__global__ __launch_bounds__(256) void prep(
    const float* __restrict__ Wq, const float* __restrict__ Wk,
    const float* __restrict__ Wv,
    unsigned short* __restrict__ Wqkb, unsigned short* __restrict__ Wvb)
{
    int i = blockIdx.x * 256 + threadIdx.x;
    if (i < 8192)       Wqkb[i] = bft(Wq[i]);
    else if (i < 16384) Wqkb[i] = bft(Wk[i - 8192]);
    Wvb[i] = bft(Wv[i]);
}

// ---------------------------------------------------------------------------
// qkv: n-tile 64 per block, 512 thr, 8 waves. q pre-scaled by log2(e).
// ---------------------------------------------------------------------------
__global__ __launch_bounds__(512) void qkv(
    const float* __restrict__ x,
    const unsigned short* __restrict__ Wqkb, const unsigned short* __restrict__ Wvb,
    const float* __restrict__ bq, const float* __restrict__ bk,
    const float* __restrict__ bv,
    unsigned short* __restrict__ qb, unsigned short* __restrict__ kb,
    unsigned short* __restrict__ vb)
{
    const int b = blockIdx.y, n0 = blockIdx.x * 64;
    const int t = threadIdx.x;
    const int lane = t & 63, w = t >> 6, c15 = lane & 15, g = lane >> 4;
    const int vr = w & 3, nh = w >> 2;

    __shared__ __align__(16) unsigned short xs[64][264];

    #pragma unroll
    for (int it = 0; it < 8; ++it) {
        int idx = t + 512 * it;
        int c = idx >> 4, q = idx & 15;
        float4 v = *(const float4*)(x + ((size_t)(b * C_ + c)) * N_ + n0 + q * 4);
        xs[q * 4 + 0][c] = bft(v.x);
        xs[q * 4 + 1][c] = bft(v.y);
        xs[q * 4 + 2][c] = bft(v.z);
        xs[q * 4 + 3][c] = bft(v.w);
    }
    __syncthreads();

    f4 qkacc[2]; f4 vacc[2][4];
    const f4 fz = {0.f, 0.f, 0.f, 0.f};
    qkacc[0] = fz; qkacc[1] = fz;
    #pragma unroll
    for (int nt = 0; nt < 2; ++nt)
        #pragma unroll
        for (int ct = 0; ct < 4; ++ct) vacc[nt][ct] = fz;

    const unsigned short* wqk = Wqkb + (vr * 16 + c15) * C_ + g * 8;
    const unsigned short* wv0 = Wvb + (vr * 64 + c15) * C_ + g * 8;
    const unsigned short* xsp = &xs[nh * 32 + c15][g * 8];

    #pragma unroll
    for (int ks = 0; ks < 8; ++ks) {
        bf8 xf0 = *(const bf8*)(xsp + ks * 32);
        bf8 xf1 = *(const bf8*)(xsp + 16 * 264 + ks * 32);
        bf8 af  = *(const bf8*)(wqk + ks * 32);
        qkacc[0] = __builtin_amdgcn_mfma_f32_16x16x32_bf16(af, xf0, qkacc[0], 0, 0, 0);
        qkacc[1] = __builtin_amdgcn_mfma_f32_16x16x32_bf16(af, xf1, qkacc[1], 0, 0, 0);
        #pragma unroll
        for (int ct = 0; ct < 4; ++ct) {
            bf8 bfv = *(const bf8*)(wv0 + ct * 16 * C_ + ks * 32);
            vacc[0][ct] = __builtin_amdgcn_mfma_f32_16x16x32_bf16(xf0, bfv, vacc[0][ct], 0, 0, 0);
            vacc[1][ct] = __builtin_amdgcn_mfma_f32_16x16x32_bf16(xf1, bfv, vacc[1][ct], 0, 0, 0);
        }
    }

    {
        float4 bias = (vr < 2) ? *(const float4*)(bq + (vr & 1) * 16 + 4 * g)
                               : *(const float4*)(bk + (vr & 1) * 16 + 4 * g);
        float sc = (vr < 2) ? 1.44269504f : 1.0f;
        unsigned short* base = (vr < 2) ? qb : kb;
        int d0 = (vr & 1) * 16 + 4 * g;
        #pragma unroll
        for (int nt = 0; nt < 2; ++nt) {
            int n = n0 + (nh * 2 + nt) * 16 + c15;
            f4 a = qkacc[nt];
            uint2 pk;
            pk.x = pk2((a.x + bias.x) * sc, (a.y + bias.y) * sc);
            pk.y = pk2((a.z + bias.z) * sc, (a.w + bias.w) * sc);
            *(uint2*)(base + ((size_t)(b * N_ + n)) * D_ + d0) = pk;
        }
    }
    #pragma unroll
    for (int ct = 0; ct < 4; ++ct) {
        int cout = vr * 64 + ct * 16 + c15;
        float bvv = bv[cout];
        #pragma unroll
        for (int nt = 0; nt < 2; ++nt) {
            f4 a = vacc[nt][ct];
            uint2 pk;
            pk.x = pk2(a.x + bvv, a.y + bvv);
            pk.y = pk2(a.z + bvv, a.w + bvv);
            *(uint2*)(vb + ((size_t)(b * C_ + cout)) * (size_t)N_
                      + n0 + (nh * 2 + nt) * 16 + 4 * g) = pk;
        }
    }
}

// ---------------------------------------------------------------------------
// attn v5: M=128, c-half 128, KT=64, 512 thr = 8 waves, grid (32,2,4)=256
// blocks; LDS 33 KB -> 2 blocks/CU. Operand-lean consume: acc[4][4] =>
// 0.5 KB operands per MFMA (the R6/R7 m=64 variants were 1 KB/MFMA — that,
// not the barrier, was the 158 us wall).
// produce: wave w owns m-frag w (16 rows), 4 n-frags (64 keys).
// consume: (mtg=w&1, ctg=(w>>1)&1, ksh=w>>2): 64m x 64c tile, 32-key half.
// P stored in XOR-swizzled 16B chunks (chunk ^ row&7): write 4/bank (min),
// b128 read 8/bank (min) — kills the 6.3M-cycle bank conflicts.
// ---------------------------------------------------------------------------
__global__ __launch_bounds__(512, 2) void attn(
    const unsigned short* __restrict__ qb, const unsigned short* __restrict__ kb,
    const unsigned short* __restrict__ vb, const float* __restrict__ x,
    const float* __restrict__ gamma, float* __restrict__ out)
{
    const int b = blockIdx.z, c0 = blockIdx.y * 128, m0 = blockIdx.x * 128;
    const int t = threadIdx.x;
    const int lane = t & 63, w = t >> 6, c15 = lane & 15, g = lane >> 4;
    const int mtg = w & 1, ctg = (w >> 1) & 1, ksh = w >> 2;   // consume role

    __shared__ __align__(16) unsigned short Ps[2][128][64];    // 32 KB, swizzled
    __shared__ float l_s[128];

    const f4 fz = {0.f, 0.f, 0.f, 0.f};
    const int swrow = c15 & 7;

    bf8 qf = *(const bf8*)(qb + ((size_t)(b * N_ + m0 + w * 16 + c15)) * D_ + g * 8);

    const unsigned short* kptr = kb + ((size_t)(b * N_ + c15)) * D_ + g * 8;
    bf8 kf[4];
    #pragma unroll
    for (int ff = 0; ff < 4; ++ff)
        kf[ff] = *(const bf8*)(kptr + (size_t)ff * 16 * D_);
    kptr += (size_t)64 * D_;

    f4 acc[4][4];
    #pragma unroll
    for (int mt = 0; mt < 4; ++mt)
        #pragma unroll
        for (int ct = 0; ct < 4; ++ct) acc[mt][ct] = fz;
    float lrun = 0.f;

    const unsigned short* vptr = vb + ((size_t)(b * C_ + c0 + ctg * 64)) * (size_t)N_
                                 + ksh * 32 + g * 8;

    for (int it = 0; it < 64; ++it) {
        const int buf = it & 1;
        // V for this iter's consume (in flight across produce + barrier)
        bf8 vf[4];
        #pragma unroll
        for (int ct = 0; ct < 4; ++ct)
            vf[ct] = *(const bf8*)(vptr + (size_t)(ct * 16 + c15) * N_);
        // produce S^T = K·Q^T (m-frag w, 64 keys)
        f4 s[4];
        #pragma unroll
        for (int ff = 0; ff < 4; ++ff)
            s[ff] = __builtin_amdgcn_mfma_f32_16x16x32_bf16(kf[ff], qf, fz, 0, 0, 0);
        // K prefetch next iter (last trip reads past kb into vb — in-bounds)
        #pragma unroll
        for (int ff = 0; ff < 4; ++ff)
            kf[ff] = *(const bf8*)(kptr + (size_t)ff * 16 * D_);
        kptr += (size_t)64 * D_;
        // exp2 (q pre-scaled by log2e), pack, swizzled P write
        char* prow = (char*)&Ps[buf][w * 16 + c15][0];
        #pragma unroll
        for (int ff = 0; ff < 4; ++ff) {
            float p0 = __builtin_amdgcn_exp2f(s[ff].x);
            float p1 = __builtin_amdgcn_exp2f(s[ff].y);
            float p2 = __builtin_amdgcn_exp2f(s[ff].z);
            float p3 = __builtin_amdgcn_exp2f(s[ff].w);
            lrun += (p0 + p1) + (p2 + p3);
            uint2 pk; pk.x = pk2(p0, p1); pk.y = pk2(p2, p3);
            int sw = (ff * 2 + (g >> 1)) ^ swrow;
            *(uint2*)(prow + sw * 16 + (g & 1) * 8) = pk;
        }
        // light barrier: drain LDS only; global loads stay in flight
        asm volatile("s_waitcnt lgkmcnt(0)\n\ts_barrier" ::: "memory");
        // consume: O += P·V^T (64m x 64c, 32-key half ksh)
        {
            const int sw = ((ksh * 4 + g) ^ swrow) * 16;
            bf8 pf[4];
            #pragma unroll
            for (int mt = 0; mt < 4; ++mt)
                pf[mt] = *(const bf8*)((char*)&Ps[buf][(mtg * 4 + mt) * 16 + c15][0] + sw);
            #pragma unroll
            for (int mt = 0; mt < 4; ++mt)
                #pragma unroll
                for (int ct = 0; ct < 4; ++ct)
                    acc[mt][ct] = __builtin_amdgcn_mfma_f32_16x16x32_bf16(pf[mt], vf[ct], acc[mt][ct], 0, 0, 0);
        }
        vptr += 64;
    }

    // l: reduce over g-groups -> full row sums (each produce wave owns its rows)
    lrun += __shfl_xor(lrun, 16);
    lrun += __shfl_xor(lrun, 32);
    if (lane < 16) l_s[w * 16 + lane] = lrun;
    __syncthreads();

    // ks-combine + epilogue in 2 rounds of 32 KB through the Ps area
    float* accs = (float*)&Ps[0][0][0];
    const float g0 = gamma[0];
    #pragma unroll
    for (int round = 0; round < 2; ++round) {
        if (ksh == 1) {
            #pragma unroll
            for (int mi = 0; mi < 2; ++mi)
                #pragma unroll
                for (int ct = 0; ct < 4; ++ct) {
                    int slot = (mtg * 2 + ctg) * 8 + mi * 4 + ct;
                    *(f4*)&accs[slot * 256 + lane * 4] = acc[round * 2 + mi][ct];
                }
        }
        __syncthreads();
        if (ksh == 0) {
            #pragma unroll
            for (int mi = 0; mi < 2; ++mi) {
                const int mt = round * 2 + mi;
                const int mrow = (mtg * 4 + mt) * 16;
                float4 lv = *(const float4*)&l_s[mrow + 4 * g];
                float i0 = 1.f / lv.x, i1 = 1.f / lv.y;
                float i2 = 1.f / lv.z, i3 = 1.f / lv.w;
                #pragma unroll
                for (int ct = 0; ct < 4; ++ct) {
                    int slot = (mtg * 2 + ctg) * 8 + mi * 4 + ct;
                    f4 o = *(const f4*)&accs[slot * 256 + lane * 4];
                    f4 a = acc[mt][ct];
                    int c = c0 + ctg * 64 + ct * 16 + c15;
                    size_t base = ((size_t)(b * C_ + c)) * (size_t)N_ + m0 + mrow + 4 * g;
                    float4 xv = *(const float4*)(x + base);
                    float4 r;
                    r.x = g0 * ((a.x + o.x) * i0) + xv.x;
                    r.y = g0 * ((a.y + o.y) * i1) + xv.y;
                    r.z = g0 * ((a.z + o.z) * i2) + xv.z;
                    r.w = g0 * ((a.w + o.w) * i3) + xv.w;
                    *(float4*)(out + base) = r;
                }
            }
        }
        __syncthreads();
    }
}

extern "C" void kernel_launch(void* const* d_in, const int* in_sizes, int n_in,
                              void* d_out, int out_size, void* d_ws, size_t ws_size,
                              hipStream_t stream) {
    const float* x     = (const float*)d_in[0];
    const float* Wq    = (const float*)d_in[1];
    const float* bq    = (const float*)d_in[2];
    const float* Wk    = (const float*)d_in[3];
    const float* bk    = (const float*)d_in[4];
    const float* Wv    = (const float*)d_in[5];
    const float* bv    = (const float*)d_in[6];
    const float* gamma = (const float*)d_in[7];
    float* out = (float*)d_out;

    unsigned short* qb   = (unsigned short*)d_ws;
    unsigned short* kb   = qb + (size_t)B_ * N_ * D_;
    unsigned short* vb   = kb + (size_t)B_ * N_ * D_;
    unsigned short* Wqkb = vb + (size_t)B_ * C_ * N_;
    unsigned short* Wvb  = Wqkb + 64 * C_;

    prep<<<256, 256, 0, stream>>>(Wq, Wk, Wv, Wqkb, Wvb);
    qkv<<<dim3(64, 4), 512, 0, stream>>>(x, Wqkb, Wvb, bq, bk, bv, qb, kb, vb);
    attn<<<dim3(32, 2, 4), 512, 0, stream>>>(qb, kb, vb, x, gamma, out);
}

// Round 9
// 184.984 us; speedup vs baseline: 1.3238x; 1.0145x over previous
//
#include <hip/hip_runtime.h>

#define B_  4
#define N_  4096   // H*W
#define C_  256
#define D_  32

typedef __attribute__((ext_vector_type(8)))  short bf8;   // 8 bf16 (4 VGPRs)
typedef __attribute__((ext_vector_type(4)))  float f4;    // 16x16 C/D frag
typedef __attribute__((ext_vector_type(16))) float f16v;  // 32x32 C/D frag

__device__ __forceinline__ unsigned short bft(float f) {
    unsigned u = __builtin_bit_cast(unsigned, f);
    return (unsigned short)((u + 0x8000u) >> 16);
}
// pack two floats to bf16x2 (a->low, b->high)
__device__ __forceinline__ unsigned pk2(float a, float b) {
    unsigned ua = __builtin_bit_cast(unsigned, a) + 0x8000u;
    unsigned ub = __builtin_bit_cast(unsigned, b) + 0x8000u;
    return __builtin_amdgcn_perm(ub, ua, 0x07060302u);
}

// ---------------------------------------------------------------------------
// prep: weights -> bf16. Wqkb[64][256] = Wq rows 0-31, Wk rows 32-63.
// ---------------------------------------------------------------------------
__global__ __launch_bounds__(256) void prep(
    const float* __restrict__ Wq, const float* __restrict__ Wk,
    const float* __restrict__ Wv,
    unsigned short* __restrict__ Wqkb, unsigned short* __restrict__ Wvb)
{
    int i = blockIdx.x * 256 + threadIdx.x;
    if (i < 8192)       Wqkb[i] = bft(Wq[i]);
    else if (i < 16384) Wqkb[i] = bft(Wk[i - 8192]);
    Wvb[i] = bft(Wv[i]);
}

// ---------------------------------------------------------------------------
// qkv: n-tile 64 per block, 512 thr, 8 waves. q pre-scaled by log2(e).
// ---------------------------------------------------------------------------
__global__ __launch_bounds__(512) void qkv(
    const float* __restrict__ x,
    const unsigned short* __restrict__ Wqkb, const unsigned short* __restrict__ Wvb,
    const float* __restrict__ bq, const float* __restrict__ bk,
    const float* __restrict__ bv,
    unsigned short* __restrict__ qb, unsigned short* __restrict__ kb,
    unsigned short* __restrict__ vb)
{
    const int b = blockIdx.y, n0 = blockIdx.x * 64;
    const int t = threadIdx.x;
    const int lane = t & 63, w = t >> 6, c15 = lane & 15, g = lane >> 4;
    const int vr = w & 3, nh = w >> 2;

    __shared__ __align__(16) unsigned short xs[64][264];

    #pragma unroll
    for (int it = 0; it < 8; ++it) {
        int idx = t + 512 * it;
        int c = idx >> 4, q = idx & 15;
        float4 v = *(const float4*)(x + ((size_t)(b * C_ + c)) * N_ + n0 + q * 4);
        xs[q * 4 + 0][c] = bft(v.x);
        xs[q * 4 + 1][c] = bft(v.y);
        xs[q * 4 + 2][c] = bft(v.z);
        xs[q * 4 + 3][c] = bft(v.w);
    }
    __syncthreads();

    f4 qkacc[2]; f4 vacc[2][4];
    const f4 fz = {0.f, 0.f, 0.f, 0.f};
    qkacc[0] = fz; qkacc[1] = fz;
    #pragma unroll
    for (int nt = 0; nt < 2; ++nt)
        #pragma unroll
        for (int ct = 0; ct < 4; ++ct) vacc[nt][ct] = fz;

    const unsigned short* wqk = Wqkb + (vr * 16 + c15) * C_ + g * 8;
    const unsigned short* wv0 = Wvb + (vr * 64 + c15) * C_ + g * 8;
    const unsigned short* xsp = &xs[nh * 32 + c15][g * 8];

    #pragma unroll
    for (int ks = 0; ks < 8; ++ks) {
        bf8 xf0 = *(const bf8*)(xsp + ks * 32);
        bf8 xf1 = *(const bf8*)(xsp + 16 * 264 + ks * 32);
        bf8 af  = *(const bf8*)(wqk + ks * 32);
        qkacc[0] = __builtin_amdgcn_mfma_f32_16x16x32_bf16(af, xf0, qkacc[0], 0, 0, 0);
        qkacc[1] = __builtin_amdgcn_mfma_f32_16x16x32_bf16(af, xf1, qkacc[1], 0, 0, 0);
        #pragma unroll
        for (int ct = 0; ct < 4; ++ct) {
            bf8 bfv = *(const bf8*)(wv0 + ct * 16 * C_ + ks * 32);
            vacc[0][ct] = __builtin_amdgcn_mfma_f32_16x16x32_bf16(xf0, bfv, vacc[0][ct], 0, 0, 0);
            vacc[1][ct] = __builtin_amdgcn_mfma_f32_16x16x32_bf16(xf1, bfv, vacc[1][ct], 0, 0, 0);
        }
    }

    {
        float4 bias = (vr < 2) ? *(const float4*)(bq + (vr & 1) * 16 + 4 * g)
                               : *(const float4*)(bk + (vr & 1) * 16 + 4 * g);
        float sc = (vr < 2) ? 1.44269504f : 1.0f;
        unsigned short* base = (vr < 2) ? qb : kb;
        int d0 = (vr & 1) * 16 + 4 * g;
        #pragma unroll
        for (int nt = 0; nt < 2; ++nt) {
            int n = n0 + (nh * 2 + nt) * 16 + c15;
            f4 a = qkacc[nt];
            uint2 pk;
            pk.x = pk2((a.x + bias.x) * sc, (a.y + bias.y) * sc);
            pk.y = pk2((a.z + bias.z) * sc, (a.w + bias.w) * sc);
            *(uint2*)(base + ((size_t)(b * N_ + n)) * D_ + d0) = pk;
        }
    }
    #pragma unroll
    for (int ct = 0; ct < 4; ++ct) {
        int cout = vr * 64 + ct * 16 + c15;
        float bvv = bv[cout];
        #pragma unroll
        for (int nt = 0; nt < 2; ++nt) {
            f4 a = vacc[nt][ct];
            uint2 pk;
            pk.x = pk2(a.x + bvv, a.y + bvv);
            pk.y = pk2(a.z + bvv, a.w + bvv);
            *(uint2*)(vb + ((size_t)(b * C_ + cout)) * (size_t)N_
                      + n0 + (nh * 2 + nt) * 16 + 4 * g) = pk;
        }
    }
}

// ---------------------------------------------------------------------------
// attn v6: 1024 thr = 16 waves = 4 waves/SIMD (the latency-hiding R4-R8
// lacked; NO second launch_bounds arg — (1024,4) caused the 64-VGPR trap).
// All MFMA 32x32x16 (2x FLOP per operand byte vs 16x16x32).
// M=128, c-half 128, KT=128, 32 iters, dbuf Ps 69.6 KB.
// produce role (pw=w&3 m-tile-32, pn=w>>2 key-chunk-32): S^T=K.Q^T 2 MFMA.
// consume role (mtg=w&1 m-64, ctg=(w>>1)&1 c-64, ksh=w>>2 key-32):
// acc[2][2] 32x32 frags (64 VGPR); 4-partial ks-combine via LDS at end.
// Layout math: P-write 4/bank, P-b128-read 8/bank (both minimal, no swizzle).
// ---------------------------------------------------------------------------
__global__ __launch_bounds__(1024) void attn(
    const unsigned short* __restrict__ qb, const unsigned short* __restrict__ kb,
    const unsigned short* __restrict__ vb, const float* __restrict__ x,
    const float* __restrict__ gamma, float* __restrict__ out)
{
    const int b = blockIdx.z, c0 = blockIdx.y * 128, m0 = blockIdx.x * 128;
    const int t = threadIdx.x;
    const int lane = t & 63, w = t >> 6, l31 = lane & 31, h = lane >> 5;
    const int pw = w & 3, pn = w >> 2;                        // produce role
    const int mtg = w & 1, ctg = (w >> 1) & 1, ksh = w >> 2;  // consume role

    __shared__ __align__(16) unsigned short Ps[2][128][136];  // 272-B rows
    __shared__ float l_s[4][128];
    __shared__ float l_sum[128];

    const f16v z16 = {0.f,0.f,0.f,0.f,0.f,0.f,0.f,0.f,
                      0.f,0.f,0.f,0.f,0.f,0.f,0.f,0.f};

    // Q B-frags (held all kernel): B[d][m], col m = l31, k = h*8+j
    const unsigned short* qrow = qb + ((size_t)(b * N_ + m0 + pw * 32 + l31)) * D_;
    bf8 qf0 = *(const bf8*)(qrow + h * 8);
    bf8 qf1 = *(const bf8*)(qrow + 16 + h * 8);

    const unsigned short* krow = kb + ((size_t)(b * N_ + pn * 32 + l31)) * D_;
    const unsigned short* vrow = vb + ((size_t)(b * C_ + c0 + ctg * 64 + l31)) * (size_t)N_
                                 + ksh * 32 + h * 8;

    f16v acc[2][2];
    acc[0][0] = z16; acc[0][1] = z16; acc[1][0] = z16; acc[1][1] = z16;
    float lrun = 0.f;

    for (int it = 0; it < 32; ++it) {
        const int buf = it & 1;
        // V B-frags for this iter's consume (in flight across produce+barrier)
        bf8 vf[2][2];
        #pragma unroll
        for (int kc = 0; kc < 2; ++kc)
            #pragma unroll
            for (int ct = 0; ct < 2; ++ct)
                vf[kc][ct] = *(const bf8*)(vrow + (size_t)ct * 32 * N_ + kc * 16);
        // K A-frags, produce S^T (32n x 32m) over D=32 in two K=16 steps
        bf8 kf0 = *(const bf8*)(krow + h * 8);
        bf8 kf1 = *(const bf8*)(krow + 16 + h * 8);
        krow += (size_t)128 * D_;
        f16v s = __builtin_amdgcn_mfma_f32_32x32x16_bf16(kf0, qf0, z16, 0, 0, 0);
        s = __builtin_amdgcn_mfma_f32_32x32x16_bf16(kf1, qf1, s, 0, 0, 0);
        // exp2 (q pre-scaled by log2e), pack, write P rows m, cols n
        {
            unsigned short* prow = &Ps[buf][pw * 32 + l31][pn * 32 + 4 * h];
            #pragma unroll
            for (int q = 0; q < 4; ++q) {
                float p0 = __builtin_amdgcn_exp2f(s[4 * q + 0]);
                float p1 = __builtin_amdgcn_exp2f(s[4 * q + 1]);
                float p2 = __builtin_amdgcn_exp2f(s[4 * q + 2]);
                float p3 = __builtin_amdgcn_exp2f(s[4 * q + 3]);
                lrun += (p0 + p1) + (p2 + p3);
                uint2 pkv; pkv.x = pk2(p0, p1); pkv.y = pk2(p2, p3);
                *(uint2*)(prow + 8 * q) = pkv;   // n = pn*32 + 8q + 4h + {0..3}
            }
        }
        // light barrier: drain LDS only; V/K global loads stay in flight
        asm volatile("s_waitcnt lgkmcnt(0)\n\ts_barrier" ::: "memory");
        // consume: O += P.V^T  (64m x 64c, keys ksh*32..+31)
        #pragma unroll
        for (int kc = 0; kc < 2; ++kc) {
            const int kcol = ksh * 32 + kc * 16 + h * 8;
            bf8 pf0 = *(const bf8*)&Ps[buf][mtg * 64 + l31][kcol];
            bf8 pf1 = *(const bf8*)&Ps[buf][mtg * 64 + 32 + l31][kcol];
            acc[0][0] = __builtin_amdgcn_mfma_f32_32x32x16_bf16(pf0, vf[kc][0], acc[0][0], 0, 0, 0);
            acc[0][1] = __builtin_amdgcn_mfma_f32_32x32x16_bf16(pf0, vf[kc][1], acc[0][1], 0, 0, 0);
            acc[1][0] = __builtin_amdgcn_mfma_f32_32x32x16_bf16(pf1, vf[kc][0], acc[1][0], 0, 0, 0);
            acc[1][1] = __builtin_amdgcn_mfma_f32_32x32x16_bf16(pf1, vf[kc][1], acc[1][1], 0, 0, 0);
        }
        vrow += 128;
    }

    // l: combine h-halves (lanes m and m+32 hold same m), publish per key-chunk
    lrun += __shfl_xor(lrun, 32);
    if (lane < 32) l_s[pn][pw * 32 + lane] = lrun;
    __syncthreads();
    if (t < 128) l_sum[t] = (l_s[0][t] + l_s[1][t]) + (l_s[2][t] + l_s[3][t]);

    // ks-combine (4 partials) + epilogue, one 32x32 frag slot per round
    float* area = (float*)&Ps[0][0][0];   // 12 slots x 64 lanes x 17 dw = 52 KB
    const float g0 = gamma[0];
    #pragma unroll
    for (int mi = 0; mi < 2; ++mi) {
        #pragma unroll
        for (int ci = 0; ci < 2; ++ci) {
            __syncthreads();
            if (ksh != 0) {
                float* dst = area + (((ksh - 1) * 4 + mtg * 2 + ctg) * 64 + lane) * 17;
                #pragma unroll
                for (int q = 0; q < 4; ++q) {
                    f4 tv = {acc[mi][ci][4*q], acc[mi][ci][4*q+1],
                             acc[mi][ci][4*q+2], acc[mi][ci][4*q+3]};
                    *(f4*)(dst + 4 * q) = tv;
                }
            }
            __syncthreads();
            if (ksh == 0) {
                f16v a = acc[mi][ci];
                #pragma unroll
                for (int p = 0; p < 3; ++p) {
                    const float* src = area + ((p * 4 + mtg * 2 + ctg) * 64 + lane) * 17;
                    #pragma unroll
                    for (int q = 0; q < 4; ++q) {
                        f4 o = *(const f4*)(src + 4 * q);
                        a[4*q+0] += o.x; a[4*q+1] += o.y;
                        a[4*q+2] += o.z; a[4*q+3] += o.w;
                    }
                }
                int c = c0 + ctg * 64 + ci * 32 + l31;
                size_t rowbase = ((size_t)(b * C_ + c)) * (size_t)N_
                                 + m0 + mtg * 64 + mi * 32;
                #pragma unroll
                for (int q = 0; q < 4; ++q) {
                    int mb = 8 * q + 4 * h;
                    float4 lv = *(const float4*)&l_sum[mtg * 64 + mi * 32 + mb];
                    float4 xv = *(const float4*)(x + rowbase + mb);
                    float4 r;
                    r.x = g0 * (a[4*q+0] / lv.x) + xv.x;
                    r.y = g0 * (a[4*q+1] / lv.y) + xv.y;
                    r.z = g0 * (a[4*q+2] / lv.z) + xv.z;
                    r.w = g0 * (a[4*q+3] / lv.w) + xv.w;
                    *(float4*)(out + rowbase + mb) = r;
                }
            }
        }
    }
}

extern "C" void kernel_launch(void* const* d_in, const int* in_sizes, int n_in,
                              void* d_out, int out_size, void* d_ws, size_t ws_size,
                              hipStream_t stream) {
    const float* x     = (const float*)d_in[0];
    const float* Wq    = (const float*)d_in[1];
    const float* bq    = (const float*)d_in[2];
    const float* Wk    = (const float*)d_in[3];
    const float* bk    = (const float*)d_in[4];
    const float* Wv    = (const float*)d_in[5];
    const float* bv    = (const float*)d_in[6];
    const float* gamma = (const float*)d_in[7];
    float* out = (float*)d_out;

    unsigned short* qb   = (unsigned short*)d_ws;
    unsigned short* kb   = qb + (size_t)B_ * N_ * D_;
    unsigned short* vb   = kb + (size_t)B_ * N_ * D_;
    unsigned short* Wqkb = vb + (size_t)B_ * C_ * N_;
    unsigned short* Wvb  = Wqkb + 64 * C_;

    prep<<<256, 256, 0, stream>>>(Wq, Wk, Wv, Wqkb, Wvb);
    qkv<<<dim3(64, 4), 512, 0, stream>>>(x, Wqkb, Wvb, bq, bk, bv, qb, kb, vb);
    attn<<<dim3(32, 2, 4), 1024, 0, stream>>>(qb, kb, vb, x, gamma, out);
}